// Round 17
// baseline (57.350 us; speedup 1.0000x reference)
//
#include <hip/hip_runtime.h>
#include <hip/hip_fp16.h>
#include <stdint.h>

// Problem constants (match reference)
#define BB 16384
#define SS 20
#define DD 128
#define EPSV 1e-5f
#define REC 32          // dwords per t-record in LDS

// R17 = R16 structure; single mechanism changed: the per-t wave-uniform
// weight stream moves from s_loads (SGPR=112 every round -> suspected
// SGPR-granule occupancy cap at ~6 waves/SIMD) to LDS staged once per block
// (2.7 KB) and read with uniform-address ds_read (broadcast, conflict-free,
// results land in VGPRs). Record t (32 dwords):
//   [0..19]  gate broadcast pairs (W[t][s], W[t][s]) f16x2
//   [20..27] conv {wc0,wb0,wa0,cw,wa2,wb2,wc2,bias} broadcast f16x2
//   [28] gate_b[t] f32   [29] pl[t]=post_w[t]*logit_w[t] f32  [30..31] pad
// plus sw[640+s]=pre_w[s], sw[660+s]=logit_w[s].
// Everything else identical to R16 (best: 52.3 us, VGPR 40, occ ~50%).
// Pre-committed reads: SGPR<=64 is the diagnostic; occupancy up + dur
// 38-46 us confirms the SGPR-cap theory; unchanged -> practical plateau.

#define BPERMU(addr, v) ((uint32_t)__builtin_amdgcn_ds_bpermute((addr), (int)(v)))

static __device__ __forceinline__ uint32_t pk16(float a, float b) {
    return __builtin_bit_cast(uint32_t, __builtin_amdgcn_cvt_pkrtz(a, b));
}
static __device__ __forceinline__ __half2 H2(uint32_t u) {
    return __builtin_bit_cast(__half2, u);
}

// ---- prep: build per-t 32-dword records in ws ----
__global__ void pack_w_kernel(const float* __restrict__ gate_w,
                              const float* __restrict__ w0, const float* __restrict__ b0,
                              const float* __restrict__ w1, const float* __restrict__ b1,
                              const float* __restrict__ w2, const float* __restrict__ b2,
                              const float* __restrict__ gate_b,
                              const float* __restrict__ post_w,
                              const float* __restrict__ logit_w,
                              uint32_t*    __restrict__ ws) {
    const int i = threadIdx.x;             // single block of 512
    if (i < SS * SS) {                     // 400 gate broadcast entries
        const int t = i / SS, s = i % SS;
        const float v = gate_w[t * SS + s];
        ws[t * REC + s] = pk16(v, v);
    }
    if (i < SS) {                          // conv + scalars for row i
        const float wa0 = w0[i*3+0], wam = w0[i*3+1], wa2 = w0[i*3+2];
        const float wb0 = w1[i*3+0], wbm = w1[i*3+1], wb2 = w1[i*3+2];
        const float wc0 = w2[i*3+0], wcm = w2[i*3+1], wc2 = w2[i*3+2];
        const float cw   = wam + wbm + wcm;
        const float bias = b0[i] + b1[i] + b2[i];
        uint32_t* o = ws + i * REC + SS;
        o[0] = pk16(wc0, wc0);  o[1] = pk16(wb0, wb0);
        o[2] = pk16(wa0, wa0);  o[3] = pk16(cw,  cw);
        o[4] = pk16(wa2, wa2);  o[5] = pk16(wb2, wb2);
        o[6] = pk16(wc2, wc2);  o[7] = pk16(bias, bias);
        o[8] = __builtin_bit_cast(uint32_t, gate_b[i]);
        o[9] = __builtin_bit_cast(uint32_t, post_w[i] * logit_w[i]);
        o[10] = 0u; o[11] = 0u;
    }
}

__global__ __launch_bounds__(256) void fused_mdt_kernel(
    const int*      __restrict__ tokens,   // [B,S]
    const float*    __restrict__ emb,      // [V,D] (6 KB, cache-resident)
    const float*    __restrict__ pre_w,    // [S]
    const float*    __restrict__ logit_w,  // [S]
    const uint32_t* __restrict__ wsg,      // per-t records (from prep)
    float*          __restrict__ out)      // [B,1,D] -> flat [B*D]
{
    __shared__ uint32_t sw[SS * REC + 2 * SS];   // 680 dwords = 2.72 KB

    const int tid  = threadIdx.x;
    const int lane = tid & 63;             // one row per wave
    const int b    = __builtin_amdgcn_readfirstlane(blockIdx.x * 4 + (tid >> 6));
    const int d0   = lane << 1;

    // ---- stage weights into LDS (once per block) ----
    for (int i = tid; i < SS * REC; i += 256) sw[i] = wsg[i];
    if (tid < SS) {
        sw[SS * REC + tid]      = __builtin_bit_cast(uint32_t, pre_w[tid]);
        sw[SS * REC + SS + tid] = __builtin_bit_cast(uint32_t, logit_w[tid]);
    }
    __syncthreads();                       // the only barrier

    // edge masks + bpermute addresses
    const bool mL1 = (lane == 0);
    const bool mL2 = (lane <  2);
    const bool mR1 = (lane == 63);
    const bool mR2 = (lane >= 62);
    const int aL2 = (lane - 2) << 2;
    const int aL1 = (lane - 1) << 2;
    const int aR1 = (lane + 1) << 2;
    const int aR2 = (lane + 2) << 2;

    const int* tb = tokens + b * SS;       // wave-uniform -> scalar loads

    // ---- pass A: stream emb for RMS stats + residual dot; store nothing ----
    float ms0 = 0.f, ms1 = 0.f, a10 = 0.f, a11 = 0.f;
    #pragma unroll
    for (int s = 0; s < SS; ++s) {
        const float2 v = *reinterpret_cast<const float2*>(emb + tb[s] * DD + d0);
        ms0 = fmaf(v.x, v.x, ms0);
        ms1 = fmaf(v.y, v.y, ms1);
        const float lw = __builtin_bit_cast(float, sw[SS * REC + SS + s]);
        a10 = fmaf(v.x, lw, a10);
        a11 = fmaf(v.y, lw, a11);
    }
    const float r0 = rsqrtf(ms0 * (1.f/SS) + EPSV);
    const float r1 = rsqrtf(ms1 * (1.f/SS) + EPSV);

    __builtin_amdgcn_sched_barrier(0);

    // ---- pass B: re-read emb (L1-hot), normalize, pack d-pairs ----
    uint32_t X[SS];
    #pragma unroll
    for (int s = 0; s < SS; ++s) {
        const float2 v = *reinterpret_cast<const float2*>(emb + tb[s] * DD + d0);
        const float pw = __builtin_bit_cast(float, sw[SS * REC + s]);
        X[s] = pk16(v.x * (r0 * pw), v.y * (r1 * pw));
    }

    __builtin_amdgcn_sched_barrier(0);

    // ---- main loop over t: 4 bperm + packed conv + packed gate + SiLU ----
    float m20 = 0.f, m21 = 0.f, ac0 = 0.f, ac1 = 0.f;
    #pragma unroll
    for (int t = 0; t < SS; ++t) {
        const uint32_t* rec = &sw[t * REC];

        uint32_t L2u = BPERMU(aL2, X[t]);
        uint32_t L1u = BPERMU(aL1, X[t]);
        uint32_t R1u = BPERMU(aR1, X[t]);
        uint32_t R2u = BPERMU(aR2, X[t]);
        L2u = mL2 ? 0u : L2u;
        L1u = mL1 ? 0u : L1u;
        R1u = mR1 ? 0u : R1u;
        R2u = mR2 ? 0u : R2u;
        const uint32_t Dm1 = __builtin_amdgcn_alignbit(X[t], L1u, 16);
        const uint32_t Dp1 = __builtin_amdgcn_alignbit(R1u, X[t], 16);

        // conv: 7 packed fma (weights = LDS broadcast reads)
        __half2 xd = H2(rec[SS + 7]);                  // bias pair
        xd = __hfma2(H2(rec[SS + 0]), H2(L2u),  xd);   // d-4
        xd = __hfma2(H2(rec[SS + 1]), H2(L1u),  xd);   // d-2
        xd = __hfma2(H2(rec[SS + 2]), H2(Dm1),  xd);   // d-1
        xd = __hfma2(H2(rec[SS + 3]), H2(X[t]), xd);   // center (merged)
        xd = __hfma2(H2(rec[SS + 4]), H2(Dp1),  xd);   // d+1
        xd = __hfma2(H2(rec[SS + 5]), H2(R1u),  xd);   // d+2
        xd = __hfma2(H2(rec[SS + 6]), H2(R2u),  xd);   // d+4

        // gate row t: 20 packed fma on broadcast pairs, 2 split chains
        __half2 ga = H2(0u), gb = H2(0u);
        #pragma unroll
        for (int s = 0; s < SS; s += 2) {
            ga = __hfma2(H2(rec[s    ]), H2(X[s    ]), ga);
            gb = __hfma2(H2(rec[s + 1]), H2(X[s + 1]), gb);
        }
        const __half2 gp = __hadd2(ga, gb);
        const float gbv = __builtin_bit_cast(float, rec[SS + 8]);
        const float g0 = __low2float(gp)  + gbv;
        const float g1 = __high2float(gp) + gbv;
        const float xd0 = __low2float(xd);
        const float xd1 = __high2float(xd);

        // SiLU + post-RMS accumulation (f32)
        const float pl = __builtin_bit_cast(float, rec[SS + 9]);
        const float h0 = xd0 * (g0 * __builtin_amdgcn_rcpf(1.f + __expf(-g0)));
        const float h1 = xd1 * (g1 * __builtin_amdgcn_rcpf(1.f + __expf(-g1)));
        m20 = fmaf(h0, h0, m20);
        m21 = fmaf(h1, h1, m21);
        ac0 = fmaf(h0, pl, ac0);
        ac1 = fmaf(h1, pl, ac1);
    }

    const float q0 = rsqrtf(m20 * (1.f/SS) + EPSV);
    const float q1 = rsqrtf(m21 * (1.f/SS) + EPSV);

    float2 res;
    res.x = a10 + q0 * ac0;
    res.y = a11 + q1 * ac1;
    *reinterpret_cast<float2*>(out + b * DD + d0) = res;
}

extern "C" void kernel_launch(void* const* d_in, const int* in_sizes, int n_in,
                              void* d_out, int out_size, void* d_ws, size_t ws_size,
                              hipStream_t stream) {
    const int*   tokens  = (const int*)  d_in[0];
    // d_in[1] = number_log — unused by the reference
    const float* emb     = (const float*)d_in[2];
    const float* pre_w   = (const float*)d_in[3];
    const float* w0      = (const float*)d_in[4];
    const float* b0      = (const float*)d_in[5];
    const float* w1      = (const float*)d_in[6];
    const float* b1      = (const float*)d_in[7];
    const float* w2      = (const float*)d_in[8];
    const float* b2      = (const float*)d_in[9];
    const float* gate_w  = (const float*)d_in[10];
    const float* gate_b  = (const float*)d_in[11];
    const float* post_w  = (const float*)d_in[12];
    const float* logit_w = (const float*)d_in[13];
    float*       out     = (float*)d_out;
    uint32_t*    ws      = (uint32_t*)d_ws;

    hipLaunchKernelGGL(pack_w_kernel, dim3(1), dim3(512), 0, stream,
                       gate_w, w0, b0, w1, b1, w2, b2,
                       gate_b, post_w, logit_w, ws);

    dim3 grid(BB / 4);   // 4 rows (4 waves) per 256-thread block
    dim3 block(256);
    hipLaunchKernelGGL(fused_mdt_kernel, grid, block, 0, stream,
                       tokens, emb, pre_w, logit_w, (const uint32_t*)ws, out);
}

// Round 18
// 50.431 us; speedup vs baseline: 1.1372x; 1.1372x over previous
//
#include <hip/hip_runtime.h>
#include <hip/hip_fp16.h>
#include <stdint.h>

// Problem constants (match reference)
#define BB 16384
#define SS 20
#define DD 128
#define EPSV 1e-5f

// R18 = R16 (best structure: one wave = 1 row, lane owns packed d-pair,
// X[20] f16x2, 4 bperm + 2 alignbit + 27 pk_fma per t, broadcast-packed
// weights via s_load) + stall-trim bundle:
//  1) SINGLE-pass prologue: pack raw x -> f16 during the stats pass, then
//     rescale packed regs with __hmul2 by (r0*pre_w, r1*pre_w) pairs.
//     Deletes pass B (20 VMEM loads/lane = half of all VMEM) and both
//     sched_barriers.
//  2) The ~12 freed VGPRs (target 44-56, same allocation tier as 40 per the
//     R13/R15/R17 occupancy-vs-VGPR curve) give the scheduler hoisting room
//     for cross-iteration bperm prefetch on its own.
// NO launch-bounds min-waves arg (R6/R12/R13). Tripwires: VGPR>64, FETCH>>1.5MB.

#define BPERMU(addr, v) ((uint32_t)__builtin_amdgcn_ds_bpermute((addr), (int)(v)))

static __device__ __forceinline__ uint32_t pk16(float a, float b) {
    return __builtin_bit_cast(uint32_t, __builtin_amdgcn_cvt_pkrtz(a, b));
}
static __device__ __forceinline__ __half2 H2(uint32_t u) {
    return __builtin_bit_cast(__half2, u);
}
static __device__ __forceinline__ uint32_t U32(__half2 h) {
    return __builtin_bit_cast(uint32_t, h);
}

// ---- prep: broadcast-pack gate_w (400) + conv weights (20x8) into ws ----
// ws[0..399]          : gwb[t*20+s] = (w[t][s], w[t][s]) f16x2
// ws[400 + t*8 + 0..7]: {wc0, wb0, wa0, cw, wa2, wb2, wc2, bias} pairs
__global__ void pack_w_kernel(const float* __restrict__ gate_w,
                              const float* __restrict__ w0, const float* __restrict__ b0,
                              const float* __restrict__ w1, const float* __restrict__ b1,
                              const float* __restrict__ w2, const float* __restrict__ b2,
                              uint32_t*    __restrict__ ws) {
    const int i = threadIdx.x;             // single block of 512
    if (i < SS * SS) {
        const float v = gate_w[i];
        ws[i] = pk16(v, v);
    }
    if (i < SS) {
        const float wa0 = w0[i*3+0], wam = w0[i*3+1], wa2 = w0[i*3+2];
        const float wb0 = w1[i*3+0], wbm = w1[i*3+1], wb2 = w1[i*3+2];
        const float wc0 = w2[i*3+0], wcm = w2[i*3+1], wc2 = w2[i*3+2];
        const float cw   = wam + wbm + wcm;
        const float bias = b0[i] + b1[i] + b2[i];
        uint32_t* o = ws + SS * SS + i * 8;
        o[0] = pk16(wc0, wc0);  o[1] = pk16(wb0, wb0);
        o[2] = pk16(wa0, wa0);  o[3] = pk16(cw,  cw);
        o[4] = pk16(wa2, wa2);  o[5] = pk16(wb2, wb2);
        o[6] = pk16(wc2, wc2);  o[7] = pk16(bias, bias);
    }
}

__global__ __launch_bounds__(256) void fused_mdt_kernel(
    const int*      __restrict__ tokens,   // [B,S]
    const float*    __restrict__ emb,      // [V,D] (6 KB, cache-resident)
    const float*    __restrict__ pre_w,    // [S]
    const uint32_t* __restrict__ wpk,      // packed weights (from prep)
    const float*    __restrict__ gate_b,   // [S]
    const float*    __restrict__ post_w,   // [S]
    const float*    __restrict__ logit_w,  // [1,S,1] -> flat [S]
    float*          __restrict__ out)      // [B,1,D] -> flat [B*D]
{
    const int tid  = threadIdx.x;
    const int lane = tid & 63;             // one row per wave
    const int b    = __builtin_amdgcn_readfirstlane(blockIdx.x * 4 + (tid >> 6));
    const int d0   = lane << 1;

    // edge masks ('same' zero padding) + bpermute addresses
    const bool mL1 = (lane == 0);
    const bool mL2 = (lane <  2);
    const bool mR1 = (lane == 63);
    const bool mR2 = (lane >= 62);
    const int aL2 = (lane - 2) << 2;
    const int aL1 = (lane - 1) << 2;
    const int aR1 = (lane + 1) << 2;
    const int aR2 = (lane + 2) << 2;

    const int* tb = tokens + b * SS;       // wave-uniform -> SGPR s_loads

    // ---- SINGLE-pass prologue: stats in f32, pack raw x -> f16 inline ----
    uint32_t X[SS];
    float ms0 = 0.f, ms1 = 0.f, a10 = 0.f, a11 = 0.f;
    #pragma unroll
    for (int s = 0; s < SS; ++s) {
        const float2 v = *reinterpret_cast<const float2*>(emb + tb[s] * DD + d0);
        ms0 = fmaf(v.x, v.x, ms0);
        ms1 = fmaf(v.y, v.y, ms1);
        const float lw = logit_w[s];
        a10 = fmaf(v.x, lw, a10);
        a11 = fmaf(v.y, lw, a11);
        X[s] = pk16(v.x, v.y);             // raw x packed; rescaled below
    }
    const float r0 = rsqrtf(ms0 * (1.f/SS) + EPSV);
    const float r1 = rsqrtf(ms1 * (1.f/SS) + EPSV);

    // rescale packed regs: X[s] *= (r0*pre_w[s], r1*pre_w[s])
    #pragma unroll
    for (int s = 0; s < SS; ++s) {
        const float pw = pre_w[s];
        X[s] = U32(__hmul2(H2(X[s]), H2(pk16(r0 * pw, r1 * pw))));
    }

    // ---- main loop over t: 4 bperm + packed conv + packed gate + SiLU ----
    float m20 = 0.f, m21 = 0.f, ac0 = 0.f, ac1 = 0.f;
    #pragma unroll
    for (int t = 0; t < SS; ++t) {
        uint32_t L2u = BPERMU(aL2, X[t]);
        uint32_t L1u = BPERMU(aL1, X[t]);
        uint32_t R1u = BPERMU(aR1, X[t]);
        uint32_t R2u = BPERMU(aR2, X[t]);
        L2u = mL2 ? 0u : L2u;
        L1u = mL1 ? 0u : L1u;
        R1u = mR1 ? 0u : R1u;
        R2u = mR2 ? 0u : R2u;
        // lane-pair splices for the +-1 taps:
        //   Dm1 = (lo = L1.hi [d0-1], hi = own.lo [d0])
        //   Dp1 = (lo = own.hi [d0+1], hi = R1.lo [d0+2])
        const uint32_t Dm1 = __builtin_amdgcn_alignbit(X[t], L1u, 16);
        const uint32_t Dp1 = __builtin_amdgcn_alignbit(R1u, X[t], 16);

        // conv: 7 packed fma via __hfma2 (weights broadcast-packed, s_load)
        const uint32_t* cw8 = wpk + SS * SS + t * 8;
        __half2 xd = H2(cw8[7]);                      // bias pair
        xd = __hfma2(H2(cw8[0]), H2(L2u),  xd);       // d-4
        xd = __hfma2(H2(cw8[1]), H2(L1u),  xd);       // d-2
        xd = __hfma2(H2(cw8[2]), H2(Dm1),  xd);       // d-1
        xd = __hfma2(H2(cw8[3]), H2(X[t]), xd);       // center (merged)
        xd = __hfma2(H2(cw8[4]), H2(Dp1),  xd);       // d+1
        xd = __hfma2(H2(cw8[5]), H2(R1u),  xd);       // d+2
        xd = __hfma2(H2(cw8[6]), H2(R2u),  xd);       // d+4

        // gate row t: 20 packed fma (__hfma2), 2 split chains; bias in f32
        __half2 ga = H2(0u), gb = H2(0u);
        #pragma unroll
        for (int q = 0; q < SS / 2; ++q) {
            ga = __hfma2(H2(wpk[t * SS + 2*q    ]), H2(X[2*q    ]), ga);
            gb = __hfma2(H2(wpk[t * SS + 2*q + 1]), H2(X[2*q + 1]), gb);
        }
        const __half2 gp = __hadd2(ga, gb);
        const float gbv = gate_b[t];
        const float g0 = __low2float(gp)  + gbv;
        const float g1 = __high2float(gp) + gbv;
        const float xd0 = __low2float(xd);
        const float xd1 = __high2float(xd);

        // SiLU + post-RMS accumulation (f32)
        const float pl = post_w[t] * logit_w[t];
        const float h0 = xd0 * (g0 * __builtin_amdgcn_rcpf(1.f + __expf(-g0)));
        const float h1 = xd1 * (g1 * __builtin_amdgcn_rcpf(1.f + __expf(-g1)));
        m20 = fmaf(h0, h0, m20);
        m21 = fmaf(h1, h1, m21);
        ac0 = fmaf(h0, pl, ac0);
        ac1 = fmaf(h1, pl, ac1);
    }

    const float q0 = rsqrtf(m20 * (1.f/SS) + EPSV);
    const float q1 = rsqrtf(m21 * (1.f/SS) + EPSV);

    float2 res;
    res.x = a10 + q0 * ac0;
    res.y = a11 + q1 * ac1;
    *reinterpret_cast<float2*>(out + b * DD + d0) = res;
}

extern "C" void kernel_launch(void* const* d_in, const int* in_sizes, int n_in,
                              void* d_out, int out_size, void* d_ws, size_t ws_size,
                              hipStream_t stream) {
    const int*   tokens  = (const int*)  d_in[0];
    // d_in[1] = number_log — unused by the reference
    const float* emb     = (const float*)d_in[2];
    const float* pre_w   = (const float*)d_in[3];
    const float* w0      = (const float*)d_in[4];
    const float* b0      = (const float*)d_in[5];
    const float* w1      = (const float*)d_in[6];
    const float* b1      = (const float*)d_in[7];
    const float* w2      = (const float*)d_in[8];
    const float* b2      = (const float*)d_in[9];
    const float* gate_w  = (const float*)d_in[10];
    const float* gate_b  = (const float*)d_in[11];
    const float* post_w  = (const float*)d_in[12];
    const float* logit_w = (const float*)d_in[13];
    float*       out     = (float*)d_out;
    uint32_t*    ws      = (uint32_t*)d_ws;

    hipLaunchKernelGGL(pack_w_kernel, dim3(1), dim3(512), 0, stream,
                       gate_w, w0, b0, w1, b1, w2, b2, ws);

    dim3 grid(BB / 4);   // 4 rows (4 waves) per 256-thread block -> 4096 blocks
    dim3 block(256);
    hipLaunchKernelGGL(fused_mdt_kernel, grid, block, 0, stream,
                       tokens, emb, pre_w, (const uint32_t*)ws,
                       gate_b, post_w, logit_w, out);
}

// Round 19
// 48.660 us; speedup vs baseline: 1.1786x; 1.0364x over previous
//
#include <hip/hip_runtime.h>
#include <hip/hip_fp16.h>
#include <stdint.h>

// Problem constants (match reference)
#define BB 16384
#define SS 20
#define DD 128
#define EPSV 1e-5f

// R19 = R18 (best: 50.4 us — single-pass prologue, one wave = 1 row, lane
// owns packed d-pair, X[20] f16x2, 4 bperm + 2 alignbit + 27 pk_fma per t)
// + PACKED f16 SiLU/post-RMS epilogue (was ~22 f32 ops/t = 1/3 of stream):
//   - gate_b seeds the packed gate accumulator (table pair) -> kills cvt+add
//   - sigmoid: hneg2 -> h2exp -> hadd2(1) -> h2rcp   (f16 exp/rcp)
//   - h = xd*g*rc as 2 hmul2; m2/ac accumulate as packed hfma2 with
//     broadcast-packed pl = post_w*logit_w from the table
//   - epilogue/t: ~22 -> ~11 ops; stream ~1300 -> ~1000 inst/wave
// Saturation safe: exp overflow -> inf -> rcp -> 0 == correct SiLU limit.
// NO launch-bounds min-waves arg. Tripwires: VGPR>64, FETCH>>1.5MB,
// absmax > 1.8e-2 (then revert m2/ac to f32).

#define BPERMU(addr, v) ((uint32_t)__builtin_amdgcn_ds_bpermute((addr), (int)(v)))

static __device__ __forceinline__ uint32_t pk16(float a, float b) {
    return __builtin_bit_cast(uint32_t, __builtin_amdgcn_cvt_pkrtz(a, b));
}
static __device__ __forceinline__ __half2 H2(uint32_t u) {
    return __builtin_bit_cast(__half2, u);
}
static __device__ __forceinline__ uint32_t U32(__half2 h) {
    return __builtin_bit_cast(uint32_t, h);
}

// ---- prep: broadcast-pack gate_w (400) + per-t 16-dword records ----
// ws[0..399]           : gwb[t*20+s] = (w[t][s], w[t][s]) f16x2
// ws[400 + t*16 + 0..7]: {wc0, wb0, wa0, cw, wa2, wb2, wc2, bias} pairs
// ws[400 + t*16 + 8]   : (gate_b[t], gate_b[t]) f16x2
// ws[400 + t*16 + 9]   : (pl, pl) f16x2 where pl = post_w[t]*logit_w[t]
__global__ void pack_w_kernel(const float* __restrict__ gate_w,
                              const float* __restrict__ w0, const float* __restrict__ b0,
                              const float* __restrict__ w1, const float* __restrict__ b1,
                              const float* __restrict__ w2, const float* __restrict__ b2,
                              const float* __restrict__ gate_b,
                              const float* __restrict__ post_w,
                              const float* __restrict__ logit_w,
                              uint32_t*    __restrict__ ws) {
    const int i = threadIdx.x;             // single block of 512
    if (i < SS * SS) {
        const float v = gate_w[i];
        ws[i] = pk16(v, v);
    }
    if (i < SS) {
        const float wa0 = w0[i*3+0], wam = w0[i*3+1], wa2 = w0[i*3+2];
        const float wb0 = w1[i*3+0], wbm = w1[i*3+1], wb2 = w1[i*3+2];
        const float wc0 = w2[i*3+0], wcm = w2[i*3+1], wc2 = w2[i*3+2];
        const float cw   = wam + wbm + wcm;
        const float bias = b0[i] + b1[i] + b2[i];
        const float gbv  = gate_b[i];
        const float pl   = post_w[i] * logit_w[i];
        uint32_t* o = ws + SS * SS + i * 16;
        o[0] = pk16(wc0, wc0);  o[1] = pk16(wb0, wb0);
        o[2] = pk16(wa0, wa0);  o[3] = pk16(cw,  cw);
        o[4] = pk16(wa2, wa2);  o[5] = pk16(wb2, wb2);
        o[6] = pk16(wc2, wc2);  o[7] = pk16(bias, bias);
        o[8] = pk16(gbv, gbv);  o[9] = pk16(pl, pl);
        o[10] = 0u; o[11] = 0u; o[12] = 0u; o[13] = 0u; o[14] = 0u; o[15] = 0u;
    }
}

__global__ __launch_bounds__(256) void fused_mdt_kernel(
    const int*      __restrict__ tokens,   // [B,S]
    const float*    __restrict__ emb,      // [V,D] (6 KB, cache-resident)
    const float*    __restrict__ pre_w,    // [S]
    const uint32_t* __restrict__ wpk,      // packed weights (from prep)
    const float*    __restrict__ logit_w,  // [1,S,1] -> flat [S]
    float*          __restrict__ out)      // [B,1,D] -> flat [B*D]
{
    const int tid  = threadIdx.x;
    const int lane = tid & 63;             // one row per wave
    const int b    = __builtin_amdgcn_readfirstlane(blockIdx.x * 4 + (tid >> 6));
    const int d0   = lane << 1;

    // edge masks ('same' zero padding) + bpermute addresses
    const bool mL1 = (lane == 0);
    const bool mL2 = (lane <  2);
    const bool mR1 = (lane == 63);
    const bool mR2 = (lane >= 62);
    const int aL2 = (lane - 2) << 2;
    const int aL1 = (lane - 1) << 2;
    const int aR1 = (lane + 1) << 2;
    const int aR2 = (lane + 2) << 2;

    const int* tb = tokens + b * SS;       // wave-uniform -> SGPR s_loads

    // ---- SINGLE-pass prologue: stats in f32, pack raw x -> f16 inline ----
    uint32_t X[SS];
    float ms0 = 0.f, ms1 = 0.f, a10 = 0.f, a11 = 0.f;
    #pragma unroll
    for (int s = 0; s < SS; ++s) {
        const float2 v = *reinterpret_cast<const float2*>(emb + tb[s] * DD + d0);
        ms0 = fmaf(v.x, v.x, ms0);
        ms1 = fmaf(v.y, v.y, ms1);
        const float lw = logit_w[s];
        a10 = fmaf(v.x, lw, a10);
        a11 = fmaf(v.y, lw, a11);
        X[s] = pk16(v.x, v.y);             // raw x packed; rescaled below
    }
    const float r0 = rsqrtf(ms0 * (1.f/SS) + EPSV);
    const float r1 = rsqrtf(ms1 * (1.f/SS) + EPSV);

    // rescale packed regs: X[s] *= (r0*pre_w[s], r1*pre_w[s])
    #pragma unroll
    for (int s = 0; s < SS; ++s) {
        const float pw = pre_w[s];
        X[s] = U32(__hmul2(H2(X[s]), H2(pk16(r0 * pw, r1 * pw))));
    }

    // ---- main loop over t: 4 bperm + packed conv/gate + PACKED SiLU ----
    const __half2 one = __float2half2_rn(1.f);
    __half2 m2pk = H2(0u), acpk = H2(0u);
    #pragma unroll
    for (int t = 0; t < SS; ++t) {
        uint32_t L2u = BPERMU(aL2, X[t]);
        uint32_t L1u = BPERMU(aL1, X[t]);
        uint32_t R1u = BPERMU(aR1, X[t]);
        uint32_t R2u = BPERMU(aR2, X[t]);
        L2u = mL2 ? 0u : L2u;
        L1u = mL1 ? 0u : L1u;
        R1u = mR1 ? 0u : R1u;
        R2u = mR2 ? 0u : R2u;
        // lane-pair splices for the +-1 taps
        const uint32_t Dm1 = __builtin_amdgcn_alignbit(X[t], L1u, 16);
        const uint32_t Dp1 = __builtin_amdgcn_alignbit(R1u, X[t], 16);

        // conv: 7 packed fma (weights broadcast-packed, s_load uniform)
        const uint32_t* rec = wpk + SS * SS + t * 16;
        __half2 xd = H2(rec[7]);                      // bias pair
        xd = __hfma2(H2(rec[0]), H2(L2u),  xd);       // d-4
        xd = __hfma2(H2(rec[1]), H2(L1u),  xd);       // d-2
        xd = __hfma2(H2(rec[2]), H2(Dm1),  xd);       // d-1
        xd = __hfma2(H2(rec[3]), H2(X[t]), xd);       // center (merged)
        xd = __hfma2(H2(rec[4]), H2(Dp1),  xd);       // d+1
        xd = __hfma2(H2(rec[5]), H2(R1u),  xd);       // d+2
        xd = __hfma2(H2(rec[6]), H2(R2u),  xd);       // d+4

        // gate row t: 20 packed fma, 2 split chains; bias seeds chain A
        __half2 ga = H2(rec[8]), gb = H2(0u);
        #pragma unroll
        for (int q = 0; q < SS / 2; ++q) {
            ga = __hfma2(H2(wpk[t * SS + 2*q    ]), H2(X[2*q    ]), ga);
            gb = __hfma2(H2(wpk[t * SS + 2*q + 1]), H2(X[2*q + 1]), gb);
        }
        const __half2 g = __hadd2(ga, gb);

        // packed SiLU: h = xd * g * rcp(1 + exp(-g))
        const __half2 e  = h2exp(__hneg2(g));
        const __half2 rc = h2rcp(__hadd2(one, e));
        const __half2 hh = __hmul2(xd, __hmul2(g, rc));

        // packed post-RMS accumulation
        m2pk = __hfma2(hh, hh, m2pk);
        acpk = __hfma2(hh, H2(rec[9]), acpk);
    }

    const float m20 = __low2float(m2pk), m21 = __high2float(m2pk);
    const float ac0 = __low2float(acpk), ac1 = __high2float(acpk);
    const float q0 = rsqrtf(m20 * (1.f/SS) + EPSV);
    const float q1 = rsqrtf(m21 * (1.f/SS) + EPSV);

    float2 res;
    res.x = a10 + q0 * ac0;
    res.y = a11 + q1 * ac1;
    *reinterpret_cast<float2*>(out + b * DD + d0) = res;
}

extern "C" void kernel_launch(void* const* d_in, const int* in_sizes, int n_in,
                              void* d_out, int out_size, void* d_ws, size_t ws_size,
                              hipStream_t stream) {
    const int*   tokens  = (const int*)  d_in[0];
    // d_in[1] = number_log — unused by the reference
    const float* emb     = (const float*)d_in[2];
    const float* pre_w   = (const float*)d_in[3];
    const float* w0      = (const float*)d_in[4];
    const float* b0      = (const float*)d_in[5];
    const float* w1      = (const float*)d_in[6];
    const float* b1      = (const float*)d_in[7];
    const float* w2      = (const float*)d_in[8];
    const float* b2      = (const float*)d_in[9];
    const float* gate_w  = (const float*)d_in[10];
    const float* gate_b  = (const float*)d_in[11];
    const float* post_w  = (const float*)d_in[12];
    const float* logit_w = (const float*)d_in[13];
    float*       out     = (float*)d_out;
    uint32_t*    ws      = (uint32_t*)d_ws;

    hipLaunchKernelGGL(pack_w_kernel, dim3(1), dim3(512), 0, stream,
                       gate_w, w0, b0, w1, b1, w2, b2,
                       gate_b, post_w, logit_w, ws);

    dim3 grid(BB / 4);   // 4 rows (4 waves) per 256-thread block -> 4096 blocks
    dim3 block(256);
    hipLaunchKernelGGL(fused_mdt_kernel, grid, block, 0, stream,
                       tokens, emb, pre_w, (const uint32_t*)ws,
                       logit_w, out);
}

// Round 20
// 47.318 us; speedup vs baseline: 1.2120x; 1.0284x over previous
//
#include <hip/hip_runtime.h>
#include <hip/hip_fp16.h>
#include <stdint.h>

// Problem constants (match reference)
#define BB 16384
#define SS 20
#define DD 128
#define EPSV 1e-5f

// R20 = R19's lean stream (single-pass prologue, packed f16 conv/gate/SiLU
// epilogue) ported to R15's 4-d/lane geometry:
//   one wave = 2 batch rows; 32 lanes/row; lane owns d0=4*il..d0+3 as
//   X0[s]=(d0,d0+1), X1[s]=(d0+2,d0+3) packed f16x2 -> 40 VGPR persistent.
// Wins vs R19: per-row DS halves (4 bperm/t serve 4 outputs), per-row
// scalar weight stream halves (both rows share t), per-row prologue halves.
// Tap map verified in R15 (passed, absmax 3.9e-3):
//   LX0=(d0-4,d0-3) LX1=(d0-2,d0-1) RX0=(d0+4,d0+5) RX1=(d0+6,d0+7)
//   Dm1=alignbit(X0,LX1,16)=(d0-1,d0)  Dc=alignbit(X1,X0,16)=(d0+1,d0+2)
//   Dp1=alignbit(RX0,X1,16)=(d0+3,d0+4)
// a1 residual accumulates as packed f16 on RAW x (lw pairs from table);
// ms stats stay f32 (safety). Target VGPR <= 64 (top occupancy tier).
// NO launch-bounds min-waves arg. Tripwires: VGPR>64, FETCH>>1.5MB,
// absmax > 1.8e-2.

#define BPERMU(addr, v) ((uint32_t)__builtin_amdgcn_ds_bpermute((addr), (int)(v)))

static __device__ __forceinline__ uint32_t pk16(float a, float b) {
    return __builtin_bit_cast(uint32_t, __builtin_amdgcn_cvt_pkrtz(a, b));
}
static __device__ __forceinline__ __half2 H2(uint32_t u) {
    return __builtin_bit_cast(__half2, u);
}
static __device__ __forceinline__ uint32_t U32(__half2 h) {
    return __builtin_bit_cast(uint32_t, h);
}

// ---- prep: broadcast-pack gate_w (400) + per-t 16-dword records ----
// ws[0..399]           : gwb[t*20+s] = (w[t][s], w[t][s]) f16x2
// ws[400 + t*16 + 0..7]: {wc0, wb0, wa0, cw, wa2, wb2, wc2, bias} pairs
// ws[400 + t*16 + 8]   : (gate_b[t], gate_b[t]) f16x2
// ws[400 + t*16 + 9]   : (pl, pl) f16x2, pl = post_w[t]*logit_w[t]
// ws[400 + t*16 + 10]  : (logit_w[t], logit_w[t]) f16x2  (for a1 accum)
__global__ void pack_w_kernel(const float* __restrict__ gate_w,
                              const float* __restrict__ w0, const float* __restrict__ b0,
                              const float* __restrict__ w1, const float* __restrict__ b1,
                              const float* __restrict__ w2, const float* __restrict__ b2,
                              const float* __restrict__ gate_b,
                              const float* __restrict__ post_w,
                              const float* __restrict__ logit_w,
                              uint32_t*    __restrict__ ws) {
    const int i = threadIdx.x;             // single block of 512
    if (i < SS * SS) {
        const float v = gate_w[i];
        ws[i] = pk16(v, v);
    }
    if (i < SS) {
        const float wa0 = w0[i*3+0], wam = w0[i*3+1], wa2 = w0[i*3+2];
        const float wb0 = w1[i*3+0], wbm = w1[i*3+1], wb2 = w1[i*3+2];
        const float wc0 = w2[i*3+0], wcm = w2[i*3+1], wc2 = w2[i*3+2];
        const float cw   = wam + wbm + wcm;
        const float bias = b0[i] + b1[i] + b2[i];
        const float gbv  = gate_b[i];
        const float pl   = post_w[i] * logit_w[i];
        const float lw   = logit_w[i];
        uint32_t* o = ws + SS * SS + i * 16;
        o[0] = pk16(wc0, wc0);  o[1] = pk16(wb0, wb0);
        o[2] = pk16(wa0, wa0);  o[3] = pk16(cw,  cw);
        o[4] = pk16(wa2, wa2);  o[5] = pk16(wb2, wb2);
        o[6] = pk16(wc2, wc2);  o[7] = pk16(bias, bias);
        o[8] = pk16(gbv, gbv);  o[9] = pk16(pl, pl);
        o[10] = pk16(lw, lw);
        o[11] = 0u; o[12] = 0u; o[13] = 0u; o[14] = 0u; o[15] = 0u;
    }
}

__global__ __launch_bounds__(256) void fused_mdt_kernel(
    const int*      __restrict__ tokens,   // [B,S]
    const float*    __restrict__ emb,      // [V,D] (6 KB, cache-resident)
    const float*    __restrict__ pre_w,    // [S]
    const uint32_t* __restrict__ wpk,      // packed weights (from prep)
    float*          __restrict__ out)      // [B,1,D] -> flat [B*D]
{
    const int tid  = threadIdx.x;
    const int lane = tid & 63;             // lane within wave
    const int il   = lane & 31;            // lane within row
    const int b    = blockIdx.x * 8 + (tid >> 5);   // one row per half-wave
    const int d0   = il << 2;

    // edge masks: il==0 kills all left taps, il==31 all right taps.
    // Half-wave boundary (lane 32's left neighbor = lane 31 of other row)
    // is exactly the il==0 masked case -> no cross-row contamination.
    const bool mL = (il == 0);
    const bool mR = (il == 31);
    const int  la = (lane - 1) << 2;
    const int  ra = (lane + 1) << 2;

    const int4* t4 = reinterpret_cast<const int4*>(tokens + b * SS);

    // ---- SINGLE-pass prologue: f32 ms stats, packed a1, pack raw x ----
    uint32_t X0[SS], X1[SS];
    float ms0=0.f, ms1=0.f, ms2=0.f, ms3=0.f;
    __half2 a1pkA = H2(0u), a1pkB = H2(0u);
    #pragma unroll
    for (int i = 0; i < 5; ++i) {
        const int4 tv = t4[i];
        const int tg[4] = {tv.x, tv.y, tv.z, tv.w};
        #pragma unroll
        for (int j = 0; j < 4; ++j) {
            const int s = 4*i + j;
            const float4 v = *reinterpret_cast<const float4*>(emb + tg[j] * DD + d0);
            ms0 = fmaf(v.x, v.x, ms0); ms1 = fmaf(v.y, v.y, ms1);
            ms2 = fmaf(v.z, v.z, ms2); ms3 = fmaf(v.w, v.w, ms3);
            const uint32_t xr0 = pk16(v.x, v.y);
            const uint32_t xr1 = pk16(v.z, v.w);
            const __half2 lwpk = H2(wpk[SS * SS + s * 16 + 10]);
            a1pkA = __hfma2(H2(xr0), lwpk, a1pkA);
            a1pkB = __hfma2(H2(xr1), lwpk, a1pkB);
            X0[s] = xr0;
            X1[s] = xr1;
        }
    }
    const float r0 = rsqrtf(ms0 * (1.f/SS) + EPSV);
    const float r1 = rsqrtf(ms1 * (1.f/SS) + EPSV);
    const float r2 = rsqrtf(ms2 * (1.f/SS) + EPSV);
    const float r3 = rsqrtf(ms3 * (1.f/SS) + EPSV);

    // rescale packed regs by (r*pre_w) pairs
    #pragma unroll
    for (int s = 0; s < SS; ++s) {
        const float pw = pre_w[s];
        X0[s] = U32(__hmul2(H2(X0[s]), H2(pk16(r0 * pw, r1 * pw))));
        X1[s] = U32(__hmul2(H2(X1[s]), H2(pk16(r2 * pw, r3 * pw))));
    }

    // ---- main loop over t: 4 bperm + 3 splice + packed conv/gate/SiLU ----
    const __half2 one = __float2half2_rn(1.f);
    __half2 m2pkA = H2(0u), m2pkB = H2(0u), acpkA = H2(0u), acpkB = H2(0u);
    #pragma unroll
    for (int t = 0; t < SS; ++t) {
        uint32_t LX0 = BPERMU(la, X0[t]);   // (d0-4, d0-3)
        uint32_t LX1 = BPERMU(la, X1[t]);   // (d0-2, d0-1)
        uint32_t RX0 = BPERMU(ra, X0[t]);   // (d0+4, d0+5)
        uint32_t RX1 = BPERMU(ra, X1[t]);   // (d0+6, d0+7)
        LX0 = mL ? 0u : LX0;  LX1 = mL ? 0u : LX1;
        RX0 = mR ? 0u : RX0;  RX1 = mR ? 0u : RX1;
        const uint32_t Dm1 = __builtin_amdgcn_alignbit(X0[t], LX1, 16);  // (d0-1, d0)
        const uint32_t Dc  = __builtin_amdgcn_alignbit(X1[t], X0[t], 16);// (d0+1, d0+2)
        const uint32_t Dp1 = __builtin_amdgcn_alignbit(RX0, X1[t], 16);  // (d0+3, d0+4)

        // conv: 14 packed fma, weights broadcast-packed (wave-uniform s_load)
        const uint32_t* rec = wpk + SS * SS + t * 16;
        __half2 xdA = H2(rec[7]);                 // chunk (d0, d0+1)
        xdA = __hfma2(H2(rec[0]), H2(LX0),   xdA);   // d-4
        xdA = __hfma2(H2(rec[1]), H2(LX1),   xdA);   // d-2
        xdA = __hfma2(H2(rec[2]), H2(Dm1),   xdA);   // d-1
        xdA = __hfma2(H2(rec[3]), H2(X0[t]), xdA);   // center (merged)
        xdA = __hfma2(H2(rec[4]), H2(Dc),    xdA);   // d+1
        xdA = __hfma2(H2(rec[5]), H2(X1[t]), xdA);   // d+2
        xdA = __hfma2(H2(rec[6]), H2(RX0),   xdA);   // d+4
        __half2 xdB = H2(rec[7]);                 // chunk (d0+2, d0+3)
        xdB = __hfma2(H2(rec[0]), H2(LX1),   xdB);   // d-4
        xdB = __hfma2(H2(rec[1]), H2(X0[t]), xdB);   // d-2
        xdB = __hfma2(H2(rec[2]), H2(Dc),    xdB);   // d-1
        xdB = __hfma2(H2(rec[3]), H2(X1[t]), xdB);   // center
        xdB = __hfma2(H2(rec[4]), H2(Dp1),   xdB);   // d+1
        xdB = __hfma2(H2(rec[5]), H2(RX0),   xdB);   // d+2
        xdB = __hfma2(H2(rec[6]), H2(RX1),   xdB);   // d+4

        // gate row t: 40 packed fma in 4 chains; bias seeds the A chains
        __half2 gaA = H2(rec[8]), gbA = H2(0u);
        __half2 gaB = H2(rec[8]), gbB = H2(0u);
        #pragma unroll
        for (int q = 0; q < SS / 2; ++q) {
            const __half2 hw0 = H2(wpk[t * SS + 2*q    ]);
            const __half2 hw1 = H2(wpk[t * SS + 2*q + 1]);
            gaA = __hfma2(hw0, H2(X0[2*q    ]), gaA);
            gbA = __hfma2(hw1, H2(X0[2*q + 1]), gbA);
            gaB = __hfma2(hw0, H2(X1[2*q    ]), gaB);
            gbB = __hfma2(hw1, H2(X1[2*q + 1]), gbB);
        }
        const __half2 gA = __hadd2(gaA, gbA);
        const __half2 gB = __hadd2(gaB, gbB);

        // packed SiLU: h = xd * g * rcp(1 + exp(-g))
        const __half2 eA  = h2exp(__hneg2(gA));
        const __half2 eB  = h2exp(__hneg2(gB));
        const __half2 rcA = h2rcp(__hadd2(one, eA));
        const __half2 rcB = h2rcp(__hadd2(one, eB));
        const __half2 hhA = __hmul2(xdA, __hmul2(gA, rcA));
        const __half2 hhB = __hmul2(xdB, __hmul2(gB, rcB));

        // packed post-RMS accumulation
        const __half2 plpk = H2(rec[9]);
        m2pkA = __hfma2(hhA, hhA, m2pkA);
        m2pkB = __hfma2(hhB, hhB, m2pkB);
        acpkA = __hfma2(hhA, plpk, acpkA);
        acpkB = __hfma2(hhB, plpk, acpkB);
    }

    const float q0 = rsqrtf(__low2float(m2pkA)  * (1.f/SS) + EPSV);
    const float q1 = rsqrtf(__high2float(m2pkA) * (1.f/SS) + EPSV);
    const float q2 = rsqrtf(__low2float(m2pkB)  * (1.f/SS) + EPSV);
    const float q3 = rsqrtf(__high2float(m2pkB) * (1.f/SS) + EPSV);

    float4 res;
    res.x = __low2float(a1pkA)  + q0 * __low2float(acpkA);
    res.y = __high2float(a1pkA) + q1 * __high2float(acpkA);
    res.z = __low2float(a1pkB)  + q2 * __low2float(acpkB);
    res.w = __high2float(a1pkB) + q3 * __high2float(acpkB);
    *reinterpret_cast<float4*>(out + b * DD + d0) = res;
}

extern "C" void kernel_launch(void* const* d_in, const int* in_sizes, int n_in,
                              void* d_out, int out_size, void* d_ws, size_t ws_size,
                              hipStream_t stream) {
    const int*   tokens  = (const int*)  d_in[0];
    // d_in[1] = number_log — unused by the reference
    const float* emb     = (const float*)d_in[2];
    const float* pre_w   = (const float*)d_in[3];
    const float* w0      = (const float*)d_in[4];
    const float* b0      = (const float*)d_in[5];
    const float* w1      = (const float*)d_in[6];
    const float* b1      = (const float*)d_in[7];
    const float* w2      = (const float*)d_in[8];
    const float* b2      = (const float*)d_in[9];
    const float* gate_w  = (const float*)d_in[10];
    const float* gate_b  = (const float*)d_in[11];
    const float* post_w  = (const float*)d_in[12];
    const float* logit_w = (const float*)d_in[13];
    float*       out     = (float*)d_out;
    uint32_t*    ws      = (uint32_t*)d_ws;

    hipLaunchKernelGGL(pack_w_kernel, dim3(1), dim3(512), 0, stream,
                       gate_w, w0, b0, w1, b1, w2, b2,
                       gate_b, post_w, logit_w, ws);

    dim3 grid(BB / 8);   // 8 rows (4 waves x 2) per 256-thread block
    dim3 block(256);
    hipLaunchKernelGGL(fused_mdt_kernel, grid, block, 0, stream,
                       tokens, emb, pre_w, (const uint32_t*)ws, out);
}